// Round 1
// baseline (537.487 us; speedup 1.0000x reference)
//
#include <hip/hip_runtime.h>
#include <cstdint>
#include <cstddef>

// Problem constants
//  B=64, N=1024, D=512, C=512, K=16, GAMMA=0.3, TEMP=0.07
#define INV_TEMP 14.285714285714285714f
#define GAMMA_ 0.3f

typedef short short8 __attribute__((ext_vector_type(8)));
typedef float floatx4 __attribute__((ext_vector_type(4)));

__device__ __forceinline__ unsigned short f2bf(float x) {
  unsigned int u = __float_as_uint(x);
  u += 0x7FFFu + ((u >> 16) & 1u);      // round-to-nearest-even
  return (unsigned short)(u >> 16);
}
__device__ __forceinline__ float bf2f(unsigned short h) {
  return __uint_as_float(((unsigned int)h) << 16);
}

// ---------------------------------------------------------------------------
// Pack patches: per-row l2-normalize [R,512] fp32, split to bf16 hi/lo.
// 1 block = 1 row, 128 threads, float4 per thread.
__global__ __launch_bounds__(128) void pack_rows_kernel(
    const float* __restrict__ src, unsigned short* __restrict__ hi,
    unsigned short* __restrict__ lo) {
  const int row = blockIdx.x;
  const int t = threadIdx.x;
  const float4 v = ((const float4*)(src + (size_t)row * 512))[t];
  float ss = v.x * v.x + v.y * v.y + v.z * v.z + v.w * v.w;
#pragma unroll
  for (int off = 32; off; off >>= 1) ss += __shfl_xor(ss, off);
  __shared__ float red[2];
  if ((t & 63) == 0) red[t >> 6] = ss;
  __syncthreads();
  const float scale = 1.0f / fmaxf(sqrtf(red[0] + red[1]), 1e-12f);
  float a0 = v.x * scale, a1 = v.y * scale, a2 = v.z * scale, a3 = v.w * scale;
  ushort4 h, l;
  h.x = f2bf(a0); l.x = f2bf(a0 - bf2f(h.x));
  h.y = f2bf(a1); l.y = f2bf(a1 - bf2f(h.y));
  h.z = f2bf(a2); l.z = f2bf(a2 - bf2f(h.z));
  h.w = f2bf(a3); l.w = f2bf(a3 - bf2f(h.w));
  ((ushort4*)(hi + (size_t)row * 512))[t] = h;
  ((ushort4*)(lo + (size_t)row * 512))[t] = l;
}

// Pack text: same + fp32 transposed copy tT[d][c] for the aff_g kernel.
__global__ __launch_bounds__(128) void pack_text_kernel(
    const float* __restrict__ src, unsigned short* __restrict__ hi,
    unsigned short* __restrict__ lo, float* __restrict__ tT) {
  const int row = blockIdx.x;  // c
  const int t = threadIdx.x;
  const float4 v = ((const float4*)(src + (size_t)row * 512))[t];
  float ss = v.x * v.x + v.y * v.y + v.z * v.z + v.w * v.w;
#pragma unroll
  for (int off = 32; off; off >>= 1) ss += __shfl_xor(ss, off);
  __shared__ float red[2];
  if ((t & 63) == 0) red[t >> 6] = ss;
  __syncthreads();
  const float scale = 1.0f / fmaxf(sqrtf(red[0] + red[1]), 1e-12f);
  float a0 = v.x * scale, a1 = v.y * scale, a2 = v.z * scale, a3 = v.w * scale;
  ushort4 h, l;
  h.x = f2bf(a0); l.x = f2bf(a0 - bf2f(h.x));
  h.y = f2bf(a1); l.y = f2bf(a1 - bf2f(h.y));
  h.z = f2bf(a2); l.z = f2bf(a2 - bf2f(h.z));
  h.w = f2bf(a3); l.w = f2bf(a3 - bf2f(h.w));
  ((ushort4*)(hi + (size_t)row * 512))[t] = h;
  ((ushort4*)(lo + (size_t)row * 512))[t] = l;
  const int d0 = t * 4;
  tT[(size_t)(d0 + 0) * 512 + row] = a0;
  tT[(size_t)(d0 + 1) * 512 + row] = a1;
  tT[(size_t)(d0 + 2) * 512 + row] = a2;
  tT[(size_t)(d0 + 3) * 512 + row] = a3;
}

// ---------------------------------------------------------------------------
// Split-bf16 3-term MFMA GEMM: logits[m][c] = A[m][:] . B[c][:], K=512.
// Block 256 thr (2x2 waves), tile 128x128, BK=32, 16x16x32 bf16 MFMA.
// LDS layout: 16B chunks (m, g) stored at chunk index m*4 + (g ^ ((m>>1)&3));
// swizzle keeps global_load_lds coalesced AND spreads ds_read_b128 frag reads
// uniformly across banks (unswizzled stride-64B would be 8-way conflicted).
__global__ __launch_bounds__(256) void gemm_split_kernel(
    const unsigned short* __restrict__ Ahi, const unsigned short* __restrict__ Alo,
    const unsigned short* __restrict__ Bhi, const unsigned short* __restrict__ Blo,
    float* __restrict__ Cout) {
  __shared__ unsigned short sAh[128 * 32], sAl[128 * 32], sBh[128 * 32], sBl[128 * 32];
  const int tid = threadIdx.x;
  const int lane = tid & 63;
  const int w = tid >> 6;
  const int wm = w >> 1, wn = w & 1;
  const int bm = blockIdx.x, bn = blockIdx.y;

  // staging: 512 chunks of 16B per array; thread handles chunks tid and 256+tid
  const int i0 = tid, i1 = 256 + tid;
  const int m0 = i0 >> 2, g0 = (i0 & 3) ^ ((m0 >> 1) & 3);
  const int m1 = i1 >> 2, g1 = (i1 & 3) ^ ((m1 >> 1) & 3);
  const unsigned aO0 = (unsigned)(bm * 128 + m0) * 512u + (unsigned)g0 * 8u;
  const unsigned aO1 = (unsigned)(bm * 128 + m1) * 512u + (unsigned)g1 * 8u;
  const unsigned bO0 = (unsigned)(bn * 128 + m0) * 512u + (unsigned)g0 * 8u;
  const unsigned bO1 = (unsigned)(bn * 128 + m1) * 512u + (unsigned)g1 * 8u;
  const unsigned ldsQ0 = (unsigned)(w * 64) * 8u;          // wave-uniform base, q=0
  const unsigned ldsQ1 = (unsigned)(256 + w * 64) * 8u;    // q=1

  // fragment LDS offsets (constant across K-slices)
  const int l15 = lane & 15, kg = lane >> 4;
  int cA[4], cB[4];
#pragma unroll
  for (int i = 0; i < 4; ++i) {
    const int ml = wm * 64 + i * 16 + l15;
    cA[i] = (ml * 4 + (kg ^ ((ml >> 1) & 3))) * 8;
    const int nl = wn * 64 + i * 16 + l15;
    cB[i] = (nl * 4 + (kg ^ ((nl >> 1) & 3))) * 8;
  }

  floatx4 acc[4][4] = {};

#define GL16(srcp, dstp)                                                        \
  __builtin_amdgcn_global_load_lds(                                             \
      (const __attribute__((address_space(1))) void*)(srcp),                    \
      (__attribute__((address_space(3))) void*)(dstp), 16, 0, 0)

  for (int ks = 0; ks < 16; ++ks) {
    const unsigned ko = (unsigned)ks * 32u;
    GL16(Ahi + aO0 + ko, sAh + ldsQ0);
    GL16(Ahi + aO1 + ko, sAh + ldsQ1);
    GL16(Alo + aO0 + ko, sAl + ldsQ0);
    GL16(Alo + aO1 + ko, sAl + ldsQ1);
    GL16(Bhi + bO0 + ko, sBh + ldsQ0);
    GL16(Bhi + bO1 + ko, sBh + ldsQ1);
    GL16(Blo + bO0 + ko, sBl + ldsQ0);
    GL16(Blo + bO1 + ko, sBl + ldsQ1);
    __syncthreads();  // compiler drains vmcnt(0) before s_barrier

    short8 ah[4], al[4], bh[4], bl[4];
#pragma unroll
    for (int i = 0; i < 4; ++i) {
      ah[i] = *(const short8*)(sAh + cA[i]);
      al[i] = *(const short8*)(sAl + cA[i]);
      bh[i] = *(const short8*)(sBh + cB[i]);
      bl[i] = *(const short8*)(sBl + cB[i]);
    }
#pragma unroll
    for (int i = 0; i < 4; ++i) {
#pragma unroll
      for (int j = 0; j < 4; ++j) {
        acc[i][j] = __builtin_amdgcn_mfma_f32_16x16x32_bf16(ah[i], bh[j], acc[i][j], 0, 0, 0);
        acc[i][j] = __builtin_amdgcn_mfma_f32_16x16x32_bf16(ah[i], bl[j], acc[i][j], 0, 0, 0);
        acc[i][j] = __builtin_amdgcn_mfma_f32_16x16x32_bf16(al[i], bh[j], acc[i][j], 0, 0, 0);
      }
    }
    __syncthreads();
  }
#undef GL16

  // epilogue: C/D layout col=lane&15, row=(lane>>4)*4+reg  [m89/m91 verified]
  const int quad = lane >> 4;
  const unsigned rowb0 = (unsigned)(bm * 128 + wm * 64 + quad * 4);
  const unsigned colb0 = (unsigned)(bn * 128 + wn * 64 + l15);
#pragma unroll
  for (int i = 0; i < 4; ++i) {
#pragma unroll
    for (int j = 0; j < 4; ++j) {
      const unsigned col = colb0 + j * 16;
#pragma unroll
      for (int r = 0; r < 4; ++r) {
        const unsigned row = rowb0 + i * 16 + r;
        Cout[(size_t)row * 512 + col] = acc[i][j][r];
      }
    }
  }
}

// ---------------------------------------------------------------------------
// Row stats: per (b,n) row of logits, max and 1/sum(exp((x-max)/T)).
// 1 wave per row, 4 rows per block.
__global__ __launch_bounds__(256) void rowstats_kernel(
    const float* __restrict__ L, float* __restrict__ rmax, float* __restrict__ rsinv) {
  const int lane = threadIdx.x & 63, w = threadIdx.x >> 6;
  const size_t m = (size_t)blockIdx.x * 4 + w;
  const float4* r4 = (const float4*)(L + m * 512);
  const float4 a = r4[lane];
  const float4 b = r4[64 + lane];
  float mx = fmaxf(fmaxf(fmaxf(a.x, a.y), fmaxf(a.z, a.w)),
                   fmaxf(fmaxf(b.x, b.y), fmaxf(b.z, b.w)));
#pragma unroll
  for (int off = 32; off; off >>= 1) mx = fmaxf(mx, __shfl_xor(mx, off));
  float s = __expf((a.x - mx) * INV_TEMP) + __expf((a.y - mx) * INV_TEMP) +
            __expf((a.z - mx) * INV_TEMP) + __expf((a.w - mx) * INV_TEMP) +
            __expf((b.x - mx) * INV_TEMP) + __expf((b.y - mx) * INV_TEMP) +
            __expf((b.z - mx) * INV_TEMP) + __expf((b.w - mx) * INV_TEMP);
#pragma unroll
  for (int off = 32; off; off >>= 1) s += __shfl_xor(s, off);
  if (lane == 0) { rmax[m] = mx; rsinv[m] = 1.0f / s; }
}

// ---------------------------------------------------------------------------
// Global affinity: per b, normalize v_cls, 512 dots vs tT (coalesced), softmax.
__global__ __launch_bounds__(256) void affg_kernel(
    const float* __restrict__ vcls, const float* __restrict__ tT,
    float* __restrict__ ag) {
  const int b = blockIdx.x, t = threadIdx.x;
  const int lane = t & 63, w = t >> 6;
  __shared__ float clsn[512];
  __shared__ float red[4];
  const float x0 = vcls[b * 512 + t];
  const float x1 = vcls[b * 512 + t + 256];
  float ss = x0 * x0 + x1 * x1;
#pragma unroll
  for (int off = 32; off; off >>= 1) ss += __shfl_xor(ss, off);
  if (lane == 0) red[w] = ss;
  __syncthreads();
  const float sc = 1.0f / fmaxf(sqrtf(red[0] + red[1] + red[2] + red[3]), 1e-12f);
  clsn[t] = x0 * sc;
  clsn[t + 256] = x1 * sc;
  __syncthreads();
  float d0 = 0.f, d1 = 0.f;
#pragma unroll 4
  for (int d = 0; d < 512; ++d) {
    const float cv = clsn[d];
    d0 = fmaf(cv, tT[(size_t)d * 512 + t], d0);
    d1 = fmaf(cv, tT[(size_t)d * 512 + t + 256], d1);
  }
  float mx = fmaxf(d0, d1);
#pragma unroll
  for (int off = 32; off; off >>= 1) mx = fmaxf(mx, __shfl_xor(mx, off));
  __syncthreads();
  if (lane == 0) red[w] = mx;
  __syncthreads();
  mx = fmaxf(fmaxf(red[0], red[1]), fmaxf(red[2], red[3]));
  const float e0 = __expf((d0 - mx) * INV_TEMP);
  const float e1 = __expf((d1 - mx) * INV_TEMP);
  float s = e0 + e1;
#pragma unroll
  for (int off = 32; off; off >>= 1) s += __shfl_xor(s, off);
  __syncthreads();
  if (lane == 0) red[w] = s;
  __syncthreads();
  const float inv = 1.0f / (red[0] + red[1] + red[2] + red[3]);
  ag[b * 512 + t] = e0 * inv;
  ag[b * 512 + t + 256] = e1 * inv;
}

// ---------------------------------------------------------------------------
// Streaming top-16 insert, branchless indexed replace (cndmask, no scratch).
__device__ __forceinline__ void topk_insert(float (&top)[16], float& vmin,
                                            int& imin, float v) {
  if (v > vmin) {
#pragma unroll
    for (int t = 0; t < 16; ++t)
      if (t == imin) top[t] = v;
    vmin = top[0]; imin = 0;
#pragma unroll
    for (int t = 1; t < 16; ++t) {
      if (top[t] < vmin) { vmin = top[t]; imin = t; }
    }
  }
}

// Partial top-16 per (b,c) over an n-chunk of 256. Thread = one c;
// block's 256 threads read 256 consecutive c per n -> coalesced 1KB.
__global__ __launch_bounds__(256) void topk_partial_kernel(
    const float* __restrict__ L, const float* __restrict__ rmax,
    const float* __restrict__ rsinv, float* __restrict__ cand) {
  const int b = blockIdx.x;
  const int c = blockIdx.y * 256 + threadIdx.x;
  const int nc = blockIdx.z;
  float top[16];
#pragma unroll
  for (int t = 0; t < 16; ++t) top[t] = -1.0f;
  float vmin = -1.0f;
  int imin = 0;
  const size_t mb = (size_t)b * 1024 + (size_t)nc * 256;
  for (int n0 = 0; n0 < 256; n0 += 4) {
    float av[4];
#pragma unroll
    for (int u = 0; u < 4; ++u) {
      const size_t m = mb + n0 + u;
      const float l = L[m * 512 + c];
      av[u] = __expf((l - rmax[m]) * INV_TEMP) * rsinv[m];
    }
#pragma unroll
    for (int u = 0; u < 4; ++u) topk_insert(top, vmin, imin, av[u]);
  }
  float* o = cand + (((size_t)b * 512 + c) * 4 + nc) * 16;
#pragma unroll
  for (int t = 0; t < 16; ++t) o[t] = top[t];
}

// Merge 4x16 candidates -> global top-16 mean, blend with aff_g.
__global__ __launch_bounds__(256) void topk_merge_kernel(
    const float* __restrict__ cand, const float* __restrict__ ag,
    float* __restrict__ out) {
  const int gid = blockIdx.x * 256 + threadIdx.x;  // b*512 + c
  const float* ci = cand + (size_t)gid * 64;
  float top[16];
#pragma unroll
  for (int t = 0; t < 16; ++t) top[t] = ci[t];
  float vmin = top[0];
  int imin = 0;
#pragma unroll
  for (int t = 1; t < 16; ++t) {
    if (top[t] < vmin) { vmin = top[t]; imin = t; }
  }
  for (int k = 16; k < 64; ++k) topk_insert(top, vmin, imin, ci[k]);
  float s = 0.f;
#pragma unroll
  for (int t = 0; t < 16; ++t) s += top[t];
  out[gid] = GAMMA_ * ag[gid] + (1.0f - GAMMA_) * (s * (1.0f / 16.0f));
}

// ---------------------------------------------------------------------------
extern "C" void kernel_launch(void* const* d_in, const int* in_sizes, int n_in,
                              void* d_out, int out_size, void* d_ws, size_t ws_size,
                              hipStream_t stream) {
  const float* vcls = (const float*)d_in[0];  // [64,512]
  const float* vpat = (const float*)d_in[1];  // [64,1024,512]
  const float* text = (const float*)d_in[2];  // [512,512]
  float* out = (float*)d_out;                 // [64,512]

  char* p = (char*)d_ws;
  auto carve = [&](size_t bytes) -> char* {
    char* r = p;
    p += (bytes + 255) & ~(size_t)255;
    return r;
  };
  unsigned short* Ahi = (unsigned short*)carve((size_t)65536 * 512 * 2);
  unsigned short* Alo = (unsigned short*)carve((size_t)65536 * 512 * 2);
  float* logits = (float*)carve((size_t)65536 * 512 * 4);
  unsigned short* Bh = (unsigned short*)carve((size_t)512 * 512 * 2);
  unsigned short* Bl = (unsigned short*)carve((size_t)512 * 512 * 2);
  float* tT = (float*)carve((size_t)512 * 512 * 4);
  float* rmax = (float*)carve((size_t)65536 * 4);
  float* rsv = (float*)carve((size_t)65536 * 4);
  float* ag = (float*)carve((size_t)64 * 512 * 4);
  float* cand = (float*)carve((size_t)64 * 512 * 4 * 16 * 4);
  if ((size_t)(p - (char*)d_ws) > ws_size) return;  // ws too small: bail loudly

  pack_text_kernel<<<512, 128, 0, stream>>>(text, Bh, Bl, tT);
  pack_rows_kernel<<<65536, 128, 0, stream>>>(vpat, Ahi, Alo);
  gemm_split_kernel<<<dim3(512, 4), 256, 0, stream>>>(Ahi, Alo, Bh, Bl, logits);
  rowstats_kernel<<<16384, 256, 0, stream>>>(logits, rmax, rsv);
  affg_kernel<<<64, 256, 0, stream>>>(vcls, tT, ag);
  topk_partial_kernel<<<dim3(64, 2, 4), 256, 0, stream>>>(logits, rmax, rsv, cand);
  topk_merge_kernel<<<128, 256, 0, stream>>>(cand, ag, out);
}

// Round 2
// 479.882 us; speedup vs baseline: 1.1200x; 1.1200x over previous
//
#include <hip/hip_runtime.h>
#include <cstdint>
#include <cstddef>

// Problem constants: B=64, N=1024, D=512, C=512, K=16, GAMMA=0.3, TEMP=0.07
#define INV_TEMP 14.285714285714285714f
#define GAMMA_ 0.3f

typedef short short8 __attribute__((ext_vector_type(8)));
typedef float floatx4 __attribute__((ext_vector_type(4)));

#if __has_builtin(__builtin_amdgcn_fmed3f)
#define MED3(v, hi, lo) __builtin_amdgcn_fmed3f((v), (hi), (lo))
#else
#define MED3(v, hi, lo) fmaxf(fminf((v), (hi)), (lo))
#endif

__device__ __forceinline__ unsigned short f2bf(float x) {
  unsigned int u = __float_as_uint(x);
  u += 0x7FFFu + ((u >> 16) & 1u);  // round-to-nearest-even
  return (unsigned short)(u >> 16);
}
__device__ __forceinline__ float bf2f(unsigned short h) {
  return __uint_as_float(((unsigned int)h) << 16);
}

// Branchless sorted-descending top-16 insert: 15 med3 + 1 max, depth-1 ILP.
__device__ __forceinline__ void insert16(float (&top)[16], float v) {
#pragma unroll
  for (int j = 15; j >= 1; --j) top[j] = MED3(v, top[j - 1], top[j]);
  top[0] = fmaxf(top[0], v);
}

// ---------------------------------------------------------------------------
// Pack patches: per-row l2-normalize [R,512] fp32, split to bf16 hi/lo.
__global__ __launch_bounds__(128) void pack_rows_kernel(
    const float* __restrict__ src, unsigned short* __restrict__ hi,
    unsigned short* __restrict__ lo) {
  const int row = blockIdx.x;
  const int t = threadIdx.x;
  const float4 v = ((const float4*)(src + (size_t)row * 512))[t];
  float ss = v.x * v.x + v.y * v.y + v.z * v.z + v.w * v.w;
#pragma unroll
  for (int off = 32; off; off >>= 1) ss += __shfl_xor(ss, off);
  __shared__ float red[2];
  if ((t & 63) == 0) red[t >> 6] = ss;
  __syncthreads();
  const float scale = 1.0f / fmaxf(sqrtf(red[0] + red[1]), 1e-12f);
  float a0 = v.x * scale, a1 = v.y * scale, a2 = v.z * scale, a3 = v.w * scale;
  ushort4 h, l;
  h.x = f2bf(a0); l.x = f2bf(a0 - bf2f(h.x));
  h.y = f2bf(a1); l.y = f2bf(a1 - bf2f(h.y));
  h.z = f2bf(a2); l.z = f2bf(a2 - bf2f(h.z));
  h.w = f2bf(a3); l.w = f2bf(a3 - bf2f(h.w));
  ((ushort4*)(hi + (size_t)row * 512))[t] = h;
  ((ushort4*)(lo + (size_t)row * 512))[t] = l;
}

// Pack text: same + fp32 transposed copy tT[d][c] for the aff_g kernel.
__global__ __launch_bounds__(128) void pack_text_kernel(
    const float* __restrict__ src, unsigned short* __restrict__ hi,
    unsigned short* __restrict__ lo, float* __restrict__ tT) {
  const int row = blockIdx.x;  // c
  const int t = threadIdx.x;
  const float4 v = ((const float4*)(src + (size_t)row * 512))[t];
  float ss = v.x * v.x + v.y * v.y + v.z * v.z + v.w * v.w;
#pragma unroll
  for (int off = 32; off; off >>= 1) ss += __shfl_xor(ss, off);
  __shared__ float red[2];
  if ((t & 63) == 0) red[t >> 6] = ss;
  __syncthreads();
  const float scale = 1.0f / fmaxf(sqrtf(red[0] + red[1]), 1e-12f);
  float a0 = v.x * scale, a1 = v.y * scale, a2 = v.z * scale, a3 = v.w * scale;
  ushort4 h, l;
  h.x = f2bf(a0); l.x = f2bf(a0 - bf2f(h.x));
  h.y = f2bf(a1); l.y = f2bf(a1 - bf2f(h.y));
  h.z = f2bf(a2); l.z = f2bf(a2 - bf2f(h.z));
  h.w = f2bf(a3); l.w = f2bf(a3 - bf2f(h.w));
  ((ushort4*)(hi + (size_t)row * 512))[t] = h;
  ((ushort4*)(lo + (size_t)row * 512))[t] = l;
  const int d0 = t * 4;
  tT[(size_t)(d0 + 0) * 512 + row] = a0;
  tT[(size_t)(d0 + 1) * 512 + row] = a1;
  tT[(size_t)(d0 + 2) * 512 + row] = a2;
  tT[(size_t)(d0 + 3) * 512 + row] = a3;
}

// ---------------------------------------------------------------------------
// Split-bf16 3-term MFMA GEMM + fused per-row softmax partial stats.
// logits[m][c] = A[m][:] . B[c][:], K=512. Block 256 thr (2x2 waves),
// tile 128x128, BK=32, 16x16x32 bf16 MFMA, XOR-swizzled 16B-chunk LDS.
// Epilogue: per row, per (bn,wn) 64-col slice -> (max, sumexp) partial.
__global__ __launch_bounds__(256) void gemm_split_kernel(
    const unsigned short* __restrict__ Ahi, const unsigned short* __restrict__ Alo,
    const unsigned short* __restrict__ Bhi, const unsigned short* __restrict__ Blo,
    float* __restrict__ Cout, float2* __restrict__ pstat) {
  __shared__ unsigned short sAh[128 * 32], sAl[128 * 32], sBh[128 * 32], sBl[128 * 32];
  const int tid = threadIdx.x;
  const int lane = tid & 63;
  const int w = tid >> 6;
  const int wm = w >> 1, wn = w & 1;
  const int bm = blockIdx.x, bn = blockIdx.y;

  const int i0 = tid, i1 = 256 + tid;
  const int m0 = i0 >> 2, g0 = (i0 & 3) ^ ((m0 >> 1) & 3);
  const int m1 = i1 >> 2, g1 = (i1 & 3) ^ ((m1 >> 1) & 3);
  const unsigned aO0 = (unsigned)(bm * 128 + m0) * 512u + (unsigned)g0 * 8u;
  const unsigned aO1 = (unsigned)(bm * 128 + m1) * 512u + (unsigned)g1 * 8u;
  const unsigned bO0 = (unsigned)(bn * 128 + m0) * 512u + (unsigned)g0 * 8u;
  const unsigned bO1 = (unsigned)(bn * 128 + m1) * 512u + (unsigned)g1 * 8u;
  const unsigned ldsQ0 = (unsigned)(w * 64) * 8u;
  const unsigned ldsQ1 = (unsigned)(256 + w * 64) * 8u;

  const int l15 = lane & 15, kg = lane >> 4;
  int cA[4], cB[4];
#pragma unroll
  for (int i = 0; i < 4; ++i) {
    const int ml = wm * 64 + i * 16 + l15;
    cA[i] = (ml * 4 + (kg ^ ((ml >> 1) & 3))) * 8;
    const int nl = wn * 64 + i * 16 + l15;
    cB[i] = (nl * 4 + (kg ^ ((nl >> 1) & 3))) * 8;
  }

  floatx4 acc[4][4] = {};

#define GL16(srcp, dstp)                                                        \
  __builtin_amdgcn_global_load_lds(                                             \
      (const __attribute__((address_space(1))) void*)(srcp),                    \
      (__attribute__((address_space(3))) void*)(dstp), 16, 0, 0)

  for (int ks = 0; ks < 16; ++ks) {
    const unsigned ko = (unsigned)ks * 32u;
    GL16(Ahi + aO0 + ko, sAh + ldsQ0);
    GL16(Ahi + aO1 + ko, sAh + ldsQ1);
    GL16(Alo + aO0 + ko, sAl + ldsQ0);
    GL16(Alo + aO1 + ko, sAl + ldsQ1);
    GL16(Bhi + bO0 + ko, sBh + ldsQ0);
    GL16(Bhi + bO1 + ko, sBh + ldsQ1);
    GL16(Blo + bO0 + ko, sBl + ldsQ0);
    GL16(Blo + bO1 + ko, sBl + ldsQ1);
    __syncthreads();

    short8 ah[4], al[4], bh[4], bl[4];
#pragma unroll
    for (int i = 0; i < 4; ++i) {
      ah[i] = *(const short8*)(sAh + cA[i]);
      al[i] = *(const short8*)(sAl + cA[i]);
      bh[i] = *(const short8*)(sBh + cB[i]);
      bl[i] = *(const short8*)(sBl + cB[i]);
    }
#pragma unroll
    for (int i = 0; i < 4; ++i) {
#pragma unroll
      for (int j = 0; j < 4; ++j) {
        acc[i][j] = __builtin_amdgcn_mfma_f32_16x16x32_bf16(ah[i], bh[j], acc[i][j], 0, 0, 0);
        acc[i][j] = __builtin_amdgcn_mfma_f32_16x16x32_bf16(ah[i], bl[j], acc[i][j], 0, 0, 0);
        acc[i][j] = __builtin_amdgcn_mfma_f32_16x16x32_bf16(al[i], bh[j], acc[i][j], 0, 0, 0);
      }
    }
    __syncthreads();
  }
#undef GL16

  // C/D layout: col=lane&15, row=(lane>>4)*4+reg  [m89/m91 verified]
  const int quad = lane >> 4;
  const unsigned rowb0 = (unsigned)(bm * 128 + wm * 64 + quad * 4);
  const unsigned colb0 = (unsigned)(bn * 128 + wn * 64 + l15);
#pragma unroll
  for (int i = 0; i < 4; ++i) {
#pragma unroll
    for (int j = 0; j < 4; ++j) {
      const unsigned col = colb0 + j * 16;
#pragma unroll
      for (int r = 0; r < 4; ++r) {
        const unsigned row = rowb0 + i * 16 + r;
        Cout[(size_t)row * 512 + col] = acc[i][j][r];
      }
    }
  }

  // Fused softmax partial stats: each wave reduces its 64-col slice per row.
  // Row (i,r) lives in the 16 lanes of this lane's quad; shfl_xor 1/2/4/8
  // stays within the 16-lane group.
  const int pk = bn * 2 + wn;  // partial slot 0..7
#pragma unroll
  for (int i = 0; i < 4; ++i) {
#pragma unroll
    for (int r = 0; r < 4; ++r) {
      float mx = fmaxf(fmaxf(acc[i][0][r], acc[i][1][r]),
                       fmaxf(acc[i][2][r], acc[i][3][r]));
      mx = fmaxf(mx, __shfl_xor(mx, 1));
      mx = fmaxf(mx, __shfl_xor(mx, 2));
      mx = fmaxf(mx, __shfl_xor(mx, 4));
      mx = fmaxf(mx, __shfl_xor(mx, 8));
      float se = __expf((acc[i][0][r] - mx) * INV_TEMP) +
                 __expf((acc[i][1][r] - mx) * INV_TEMP) +
                 __expf((acc[i][2][r] - mx) * INV_TEMP) +
                 __expf((acc[i][3][r] - mx) * INV_TEMP);
      se += __shfl_xor(se, 1);
      se += __shfl_xor(se, 2);
      se += __shfl_xor(se, 4);
      se += __shfl_xor(se, 8);
      if (l15 == 0) {
        const unsigned row = rowb0 + i * 16 + r;
        pstat[(size_t)row * 8 + pk] = make_float2(mx, se);
      }
    }
  }
}

// ---------------------------------------------------------------------------
// Combine 8 partials per row -> LW[m] = -(ln(S) + gmax*invT).
// aff[m][c] = exp(logit*invT + LW[m]); top-k compares s = fma(l,invT,LW).
__global__ __launch_bounds__(256) void lw_kernel(
    const float2* __restrict__ pstat, float* __restrict__ LW) {
  const int m = blockIdx.x * 256 + threadIdx.x;
  const float2* p = pstat + (size_t)m * 8;
  float2 v[8];
#pragma unroll
  for (int k = 0; k < 8; ++k) v[k] = p[k];
  float gmax = v[0].x;
#pragma unroll
  for (int k = 1; k < 8; ++k) gmax = fmaxf(gmax, v[k].x);
  float S = 0.f;
#pragma unroll
  for (int k = 0; k < 8; ++k) S += v[k].y * __expf((v[k].x - gmax) * INV_TEMP);
  LW[m] = -(__logf(S) + gmax * INV_TEMP);
}

// ---------------------------------------------------------------------------
// Global affinity: per b, normalize v_cls, 512 dots vs tT (coalesced), softmax.
__global__ __launch_bounds__(256) void affg_kernel(
    const float* __restrict__ vcls, const float* __restrict__ tT,
    float* __restrict__ ag) {
  const int b = blockIdx.x, t = threadIdx.x;
  const int lane = t & 63, w = t >> 6;
  __shared__ float clsn[512];
  __shared__ float red[4];
  const float x0 = vcls[b * 512 + t];
  const float x1 = vcls[b * 512 + t + 256];
  float ss = x0 * x0 + x1 * x1;
#pragma unroll
  for (int off = 32; off; off >>= 1) ss += __shfl_xor(ss, off);
  if (lane == 0) red[w] = ss;
  __syncthreads();
  const float sc = 1.0f / fmaxf(sqrtf(red[0] + red[1] + red[2] + red[3]), 1e-12f);
  clsn[t] = x0 * sc;
  clsn[t + 256] = x1 * sc;
  __syncthreads();
  float d0 = 0.f, d1 = 0.f;
#pragma unroll 4
  for (int d = 0; d < 512; ++d) {
    const float cv = clsn[d];
    d0 = fmaf(cv, tT[(size_t)d * 512 + t], d0);
    d1 = fmaf(cv, tT[(size_t)d * 512 + t + 256], d1);
  }
  float mx = fmaxf(d0, d1);
#pragma unroll
  for (int off = 32; off; off >>= 1) mx = fmaxf(mx, __shfl_xor(mx, off));
  __syncthreads();
  if (lane == 0) red[w] = mx;
  __syncthreads();
  mx = fmaxf(fmaxf(red[0], red[1]), fmaxf(red[2], red[3]));
  const float e0 = __expf((d0 - mx) * INV_TEMP);
  const float e1 = __expf((d1 - mx) * INV_TEMP);
  float s = e0 + e1;
#pragma unroll
  for (int off = 32; off; off >>= 1) s += __shfl_xor(s, off);
  __syncthreads();
  if (lane == 0) red[w] = s;
  __syncthreads();
  const float inv = 1.0f / (red[0] + red[1] + red[2] + red[3]);
  ag[b * 512 + t] = e0 * inv;
  ag[b * 512 + t + 256] = e1 * inv;
}

// ---------------------------------------------------------------------------
// Partial top-16 per (b,c) over an n-chunk of 128, in s = l*invT + LW[n]
// domain (no exp in inner loop). Thread = one c; coalesced column reads.
// cand layout [b][chunk][t][c] so both write and merge-read are coalesced.
__global__ __launch_bounds__(256) void topk_partial_kernel(
    const float* __restrict__ L, const float* __restrict__ LW,
    float* __restrict__ cand) {
  const int b = blockIdx.x;
  const int c = blockIdx.y * 256 + threadIdx.x;
  const int nc = blockIdx.z;
  float top[16];
#pragma unroll
  for (int t = 0; t < 16; ++t) top[t] = -3.0e38f;
  const size_t mb = (size_t)b * 1024 + (size_t)nc * 128;
  const float* Lp = L + mb * 512 + c;
  const float* Wp = LW + mb;
  for (int n0 = 0; n0 < 128; n0 += 4) {
    float s0 = fmaf(Lp[(size_t)(n0 + 0) * 512], INV_TEMP, Wp[n0 + 0]);
    float s1 = fmaf(Lp[(size_t)(n0 + 1) * 512], INV_TEMP, Wp[n0 + 1]);
    float s2 = fmaf(Lp[(size_t)(n0 + 2) * 512], INV_TEMP, Wp[n0 + 2]);
    float s3 = fmaf(Lp[(size_t)(n0 + 3) * 512], INV_TEMP, Wp[n0 + 3]);
    insert16(top, s0);
    insert16(top, s1);
    insert16(top, s2);
    insert16(top, s3);
  }
  float* o = cand + ((size_t)b * 8 + nc) * 16 * 512 + c;
#pragma unroll
  for (int t = 0; t < 16; ++t) o[(size_t)t * 512] = top[t];
}

// Merge 8x16 s-candidates -> top-16, exp, mean, blend with aff_g.
__global__ __launch_bounds__(256) void topk_merge_kernel(
    const float* __restrict__ cand, const float* __restrict__ ag,
    float* __restrict__ out) {
  const int gid = blockIdx.x * 256 + threadIdx.x;  // b*512 + c
  const int b = gid >> 9, c = gid & 511;
  const float* cb = cand + (size_t)b * 128 * 512 + c;
  float top[16];
#pragma unroll
  for (int t = 0; t < 16; ++t) top[t] = -3.0e38f;
  for (int k = 0; k < 128; ++k) insert16(top, cb[(size_t)k * 512]);
  float s = 0.f;
#pragma unroll
  for (int t = 0; t < 16; ++t) s += __expf(top[t]);
  out[gid] = GAMMA_ * ag[gid] + (1.0f - GAMMA_) * (s * (1.0f / 16.0f));
}

// ---------------------------------------------------------------------------
extern "C" void kernel_launch(void* const* d_in, const int* in_sizes, int n_in,
                              void* d_out, int out_size, void* d_ws, size_t ws_size,
                              hipStream_t stream) {
  const float* vcls = (const float*)d_in[0];  // [64,512]
  const float* vpat = (const float*)d_in[1];  // [64,1024,512]
  const float* text = (const float*)d_in[2];  // [512,512]
  float* out = (float*)d_out;                 // [64,512]

  char* p = (char*)d_ws;
  auto carve = [&](size_t bytes) -> char* {
    char* r = p;
    p += (bytes + 255) & ~(size_t)255;
    return r;
  };
  unsigned short* Ahi = (unsigned short*)carve((size_t)65536 * 512 * 2);
  unsigned short* Alo = (unsigned short*)carve((size_t)65536 * 512 * 2);
  float* logits = (float*)carve((size_t)65536 * 512 * 4);
  unsigned short* Bh = (unsigned short*)carve((size_t)512 * 512 * 2);
  unsigned short* Bl = (unsigned short*)carve((size_t)512 * 512 * 2);
  float* tT = (float*)carve((size_t)512 * 512 * 4);
  float2* pstat = (float2*)carve((size_t)65536 * 8 * 8);
  float* LW = (float*)carve((size_t)65536 * 4);
  float* ag = (float*)carve((size_t)64 * 512 * 4);
  // cand [64][8][16][512] f32 = 16.8 MB aliases Ahi (dead after gemm).
  float* cand = (float*)Ahi;
  if ((size_t)(p - (char*)d_ws) > ws_size) return;

  pack_text_kernel<<<512, 128, 0, stream>>>(text, Bh, Bl, tT);
  pack_rows_kernel<<<65536, 128, 0, stream>>>(vpat, Ahi, Alo);
  gemm_split_kernel<<<dim3(512, 4), 256, 0, stream>>>(Ahi, Alo, Bh, Bl, logits, pstat);
  lw_kernel<<<256, 256, 0, stream>>>(pstat, LW);
  affg_kernel<<<64, 256, 0, stream>>>(vcls, tT, ag);
  topk_partial_kernel<<<dim3(64, 2, 8), 256, 0, stream>>>(logits, LW, cand);
  topk_merge_kernel<<<128, 256, 0, stream>>>(cand, ag, out);
}

// Round 3
// 395.863 us; speedup vs baseline: 1.3578x; 1.2122x over previous
//
#include <hip/hip_runtime.h>
#include <cstdint>
#include <cstddef>

// Problem constants: B=64, N=1024, D=512, C=512, K=16, GAMMA=0.3, TEMP=0.07
#define INV_TEMP 14.285714285714285714f
#define GAMMA_ 0.3f

// A-matrix row layout: rows 0..65535 = patches (b*1024+n); rows 65536..65599
// = cls per b; rows 65600..65663 = zero padding (tile 512 of 513).
#define ROWS_PAD 65664

typedef short short8 __attribute__((ext_vector_type(8)));
typedef float floatx4 __attribute__((ext_vector_type(4)));

#if __has_builtin(__builtin_amdgcn_fmed3f)
#define MED3(v, hi, lo) __builtin_amdgcn_fmed3f((v), (hi), (lo))
#else
#define MED3(v, hi, lo) fmaxf(fminf((v), (hi)), (lo))
#endif

__device__ __forceinline__ unsigned short f2bf(float x) {
  unsigned int u = __float_as_uint(x);
  u += 0x7FFFu + ((u >> 16) & 1u);  // round-to-nearest-even
  return (unsigned short)(u >> 16);
}
__device__ __forceinline__ float bf2f(unsigned short h) {
  return __uint_as_float(((unsigned int)h) << 16);
}

// Branchless sorted-descending top-16 insert: 15 med3 + 1 max, depth-1 ILP.
__device__ __forceinline__ void insert16(float (&top)[16], float v) {
#pragma unroll
  for (int j = 15; j >= 1; --j) top[j] = MED3(v, top[j - 1], top[j]);
  top[0] = fmaxf(top[0], v);
}

// ---------------------------------------------------------------------------
// Pack patches: per-row l2-normalize [R,512] fp32, split to bf16 hi/lo.
__global__ __launch_bounds__(128) void pack_rows_kernel(
    const float* __restrict__ src, unsigned short* __restrict__ hi,
    unsigned short* __restrict__ lo) {
  const int row = blockIdx.x;
  const int t = threadIdx.x;
  const float4 v = ((const float4*)(src + (size_t)row * 512))[t];
  float ss = v.x * v.x + v.y * v.y + v.z * v.z + v.w * v.w;
#pragma unroll
  for (int off = 32; off; off >>= 1) ss += __shfl_xor(ss, off);
  __shared__ float red[2];
  if ((t & 63) == 0) red[t >> 6] = ss;
  __syncthreads();
  const float scale = 1.0f / fmaxf(sqrtf(red[0] + red[1]), 1e-12f);
  float a0 = v.x * scale, a1 = v.y * scale, a2 = v.z * scale, a3 = v.w * scale;
  ushort4 h, l;
  h.x = f2bf(a0); l.x = f2bf(a0 - bf2f(h.x));
  h.y = f2bf(a1); l.y = f2bf(a1 - bf2f(h.y));
  h.z = f2bf(a2); l.z = f2bf(a2 - bf2f(h.z));
  h.w = f2bf(a3); l.w = f2bf(a3 - bf2f(h.w));
  ((ushort4*)(hi + (size_t)row * 512))[t] = h;
  ((ushort4*)(lo + (size_t)row * 512))[t] = l;
}

// Pack text rows (B matrix): l2-normalize + hi/lo split.
__global__ __launch_bounds__(128) void pack_text_kernel(
    const float* __restrict__ src, unsigned short* __restrict__ hi,
    unsigned short* __restrict__ lo) {
  const int row = blockIdx.x;
  const int t = threadIdx.x;
  const float4 v = ((const float4*)(src + (size_t)row * 512))[t];
  float ss = v.x * v.x + v.y * v.y + v.z * v.z + v.w * v.w;
#pragma unroll
  for (int off = 32; off; off >>= 1) ss += __shfl_xor(ss, off);
  __shared__ float red[2];
  if ((t & 63) == 0) red[t >> 6] = ss;
  __syncthreads();
  const float scale = 1.0f / fmaxf(sqrtf(red[0] + red[1]), 1e-12f);
  float a0 = v.x * scale, a1 = v.y * scale, a2 = v.z * scale, a3 = v.w * scale;
  ushort4 h, l;
  h.x = f2bf(a0); l.x = f2bf(a0 - bf2f(h.x));
  h.y = f2bf(a1); l.y = f2bf(a1 - bf2f(h.y));
  h.z = f2bf(a2); l.z = f2bf(a2 - bf2f(h.z));
  h.w = f2bf(a3); l.w = f2bf(a3 - bf2f(h.w));
  ((ushort4*)(hi + (size_t)row * 512))[t] = h;
  ((ushort4*)(lo + (size_t)row * 512))[t] = l;
}

// Pack cls rows into A rows 65536..65663 (64 real + 64 zero-pad).
__global__ __launch_bounds__(128) void pack_cls_kernel(
    const float* __restrict__ vcls, unsigned short* __restrict__ hi,
    unsigned short* __restrict__ lo) {
  const int row = blockIdx.x;  // 0..127
  const int t = threadIdx.x;
  const size_t obase = ((size_t)65536 + row) * 512;
  if (row < 64) {
    const float4 v = ((const float4*)(vcls + (size_t)row * 512))[t];
    float ss = v.x * v.x + v.y * v.y + v.z * v.z + v.w * v.w;
#pragma unroll
    for (int off = 32; off; off >>= 1) ss += __shfl_xor(ss, off);
    __shared__ float red[2];
    if ((t & 63) == 0) red[t >> 6] = ss;
    __syncthreads();
    const float scale = 1.0f / fmaxf(sqrtf(red[0] + red[1]), 1e-12f);
    float a0 = v.x * scale, a1 = v.y * scale, a2 = v.z * scale, a3 = v.w * scale;
    ushort4 h, l;
    h.x = f2bf(a0); l.x = f2bf(a0 - bf2f(h.x));
    h.y = f2bf(a1); l.y = f2bf(a1 - bf2f(h.y));
    h.z = f2bf(a2); l.z = f2bf(a2 - bf2f(h.z));
    h.w = f2bf(a3); l.w = f2bf(a3 - bf2f(h.w));
    ((ushort4*)(hi + obase))[t] = h;
    ((ushort4*)(lo + obase))[t] = l;
  } else {
    const ushort4 z = {0, 0, 0, 0};
    ((ushort4*)(hi + obase))[t] = z;
    ((ushort4*)(lo + obase))[t] = z;
  }
}

// ---------------------------------------------------------------------------
// Split-bf16 3-term MFMA GEMM + slim fused softmax partial sum.
// logits[m][c] = A[m][:] . B[c][:], K=512. Block 256 thr (2x2 waves),
// tile 128x128, BK=32, 16x16x32 bf16 MFMA, XOR-swizzled 16B-chunk LDS.
// Since rows are l2-normalized, |logit| <= 1: partial sumexp uses the FIXED
// max 1.0 (exp((l-1)*invT) >= e^-28.6, no under/overflow) -> no max-reduce,
// scalar pstat. Grid (bn=4, bm=513): A-tile-sharing blocks dispatch
// adjacently for L2/L3 reuse.
__global__ __launch_bounds__(256) void gemm_split_kernel(
    const unsigned short* __restrict__ Ahi, const unsigned short* __restrict__ Alo,
    const unsigned short* __restrict__ Bhi, const unsigned short* __restrict__ Blo,
    float* __restrict__ Cout, float* __restrict__ pstat) {
  __shared__ unsigned short sAh[128 * 32], sAl[128 * 32], sBh[128 * 32], sBl[128 * 32];
  const int tid = threadIdx.x;
  const int lane = tid & 63;
  const int w = tid >> 6;
  const int wm = w >> 1, wn = w & 1;
  const int bn = blockIdx.x, bm = blockIdx.y;

  const int i0 = tid, i1 = 256 + tid;
  const int m0 = i0 >> 2, g0 = (i0 & 3) ^ ((m0 >> 1) & 3);
  const int m1 = i1 >> 2, g1 = (i1 & 3) ^ ((m1 >> 1) & 3);
  const unsigned aO0 = (unsigned)(bm * 128 + m0) * 512u + (unsigned)g0 * 8u;
  const unsigned aO1 = (unsigned)(bm * 128 + m1) * 512u + (unsigned)g1 * 8u;
  const unsigned bO0 = (unsigned)(bn * 128 + m0) * 512u + (unsigned)g0 * 8u;
  const unsigned bO1 = (unsigned)(bn * 128 + m1) * 512u + (unsigned)g1 * 8u;
  const unsigned ldsQ0 = (unsigned)(w * 64) * 8u;
  const unsigned ldsQ1 = (unsigned)(256 + w * 64) * 8u;

  const int l15 = lane & 15, kg = lane >> 4;
  int cA[4], cB[4];
#pragma unroll
  for (int i = 0; i < 4; ++i) {
    const int ml = wm * 64 + i * 16 + l15;
    cA[i] = (ml * 4 + (kg ^ ((ml >> 1) & 3))) * 8;
    const int nl = wn * 64 + i * 16 + l15;
    cB[i] = (nl * 4 + (kg ^ ((nl >> 1) & 3))) * 8;
  }

  floatx4 acc[4][4] = {};

#define GL16(srcp, dstp)                                                        \
  __builtin_amdgcn_global_load_lds(                                             \
      (const __attribute__((address_space(1))) void*)(srcp),                    \
      (__attribute__((address_space(3))) void*)(dstp), 16, 0, 0)

  for (int ks = 0; ks < 16; ++ks) {
    const unsigned ko = (unsigned)ks * 32u;
    GL16(Ahi + aO0 + ko, sAh + ldsQ0);
    GL16(Ahi + aO1 + ko, sAh + ldsQ1);
    GL16(Alo + aO0 + ko, sAl + ldsQ0);
    GL16(Alo + aO1 + ko, sAl + ldsQ1);
    GL16(Bhi + bO0 + ko, sBh + ldsQ0);
    GL16(Bhi + bO1 + ko, sBh + ldsQ1);
    GL16(Blo + bO0 + ko, sBl + ldsQ0);
    GL16(Blo + bO1 + ko, sBl + ldsQ1);
    __syncthreads();

    short8 ah[4], al[4], bh[4], bl[4];
#pragma unroll
    for (int i = 0; i < 4; ++i) {
      ah[i] = *(const short8*)(sAh + cA[i]);
      al[i] = *(const short8*)(sAl + cA[i]);
      bh[i] = *(const short8*)(sBh + cB[i]);
      bl[i] = *(const short8*)(sBl + cB[i]);
    }
#pragma unroll
    for (int i = 0; i < 4; ++i) {
#pragma unroll
      for (int j = 0; j < 4; ++j) {
        acc[i][j] = __builtin_amdgcn_mfma_f32_16x16x32_bf16(ah[i], bh[j], acc[i][j], 0, 0, 0);
        acc[i][j] = __builtin_amdgcn_mfma_f32_16x16x32_bf16(ah[i], bl[j], acc[i][j], 0, 0, 0);
        acc[i][j] = __builtin_amdgcn_mfma_f32_16x16x32_bf16(al[i], bh[j], acc[i][j], 0, 0, 0);
      }
    }
    __syncthreads();
  }
#undef GL16

  // C/D layout: col=lane&15, row=(lane>>4)*4+reg  [m89/m91 verified]
  const int quad = lane >> 4;
  const unsigned rowb0 = (unsigned)(bm * 128 + wm * 64 + quad * 4);
  const unsigned colb0 = (unsigned)(bn * 128 + wn * 64 + l15);
#pragma unroll
  for (int i = 0; i < 4; ++i) {
#pragma unroll
    for (int j = 0; j < 4; ++j) {
      const unsigned col = colb0 + j * 16;
#pragma unroll
      for (int r = 0; r < 4; ++r) {
        const unsigned row = rowb0 + i * 16 + r;
        Cout[(size_t)row * 512 + col] = acc[i][j][r];
      }
    }
  }

  // Slim fused partial sumexp (fixed max=1.0): 16-lane quad shfl-sum only.
  const int pk = bn * 2 + wn;  // slot 0..7
#pragma unroll
  for (int i = 0; i < 4; ++i) {
#pragma unroll
    for (int r = 0; r < 4; ++r) {
      float se = __expf((acc[i][0][r] - 1.0f) * INV_TEMP) +
                 __expf((acc[i][1][r] - 1.0f) * INV_TEMP) +
                 __expf((acc[i][2][r] - 1.0f) * INV_TEMP) +
                 __expf((acc[i][3][r] - 1.0f) * INV_TEMP);
      se += __shfl_xor(se, 1);
      se += __shfl_xor(se, 2);
      se += __shfl_xor(se, 4);
      se += __shfl_xor(se, 8);
      if (l15 == 0) {
        const unsigned row = rowb0 + i * 16 + r;
        pstat[(size_t)row * 8 + pk] = se;
      }
    }
  }
}

// ---------------------------------------------------------------------------
// LW[m] = -(ln(sum_pk pstat) + invT); aff[m][c] = exp(fma(l, invT, LW[m])).
__global__ __launch_bounds__(256) void lw_kernel(
    const float* __restrict__ pstat, float* __restrict__ LW) {
  const int m = blockIdx.x * 256 + threadIdx.x;
  const float* p = pstat + (size_t)m * 8;
  float S = 0.f;
#pragma unroll
  for (int k = 0; k < 8; ++k) S += p[k];
  LW[m] = -(__logf(S) + INV_TEMP);
}

// ---------------------------------------------------------------------------
// Partial top-16 per (b,c) over an n-chunk of 128, in s = l*invT + LW[n]
// domain (no exp in inner loop). Thread = one c; coalesced column reads.
__global__ __launch_bounds__(256) void topk_partial_kernel(
    const float* __restrict__ L, const float* __restrict__ LW,
    float* __restrict__ cand) {
  const int b = blockIdx.x;
  const int c = blockIdx.y * 256 + threadIdx.x;
  const int nc = blockIdx.z;
  float top[16];
#pragma unroll
  for (int t = 0; t < 16; ++t) top[t] = -3.0e38f;
  const size_t mb = (size_t)b * 1024 + (size_t)nc * 128;
  const float* Lp = L + mb * 512 + c;
  const float* Wp = LW + mb;
  for (int n0 = 0; n0 < 128; n0 += 8) {
    float s[8];
#pragma unroll
    for (int u = 0; u < 8; ++u)
      s[u] = fmaf(Lp[(size_t)(n0 + u) * 512], INV_TEMP, Wp[n0 + u]);
#pragma unroll
    for (int u = 0; u < 8; ++u) insert16(top, s[u]);
  }
  float* o = cand + ((size_t)b * 8 + nc) * 16 * 512 + c;
#pragma unroll
  for (int t = 0; t < 16; ++t) o[(size_t)t * 512] = top[t];
}

// Merge 8x16 s-candidates -> top-16 mean; fused aff_g from cls logit rows.
__global__ __launch_bounds__(256) void topk_merge_kernel(
    const float* __restrict__ cand, const float* __restrict__ logits,
    const float* __restrict__ LW, float* __restrict__ out) {
  const int gid = blockIdx.x * 256 + threadIdx.x;  // b*512 + c
  const int b = gid >> 9, c = gid & 511;
  const float* cb = cand + (size_t)b * 128 * 512 + c;
  float top[16];
#pragma unroll
  for (int t = 0; t < 16; ++t) top[t] = -3.0e38f;
  for (int kb = 0; kb < 8; ++kb) {
    float v[16];
#pragma unroll
    for (int j = 0; j < 16; ++j) v[j] = cb[(size_t)(kb * 16 + j) * 512];
#pragma unroll
    for (int j = 0; j < 16; ++j) insert16(top, v[j]);
  }
  float s = 0.f;
#pragma unroll
  for (int t = 0; t < 16; ++t) s += __expf(top[t]);
  const float lg = logits[((size_t)65536 + b) * 512 + c];
  const float ag = __expf(fmaf(lg, INV_TEMP, LW[65536 + b]));
  out[gid] = GAMMA_ * ag + (1.0f - GAMMA_) * (s * (1.0f / 16.0f));
}

// ---------------------------------------------------------------------------
extern "C" void kernel_launch(void* const* d_in, const int* in_sizes, int n_in,
                              void* d_out, int out_size, void* d_ws, size_t ws_size,
                              hipStream_t stream) {
  const float* vcls = (const float*)d_in[0];  // [64,512]
  const float* vpat = (const float*)d_in[1];  // [64,1024,512]
  const float* text = (const float*)d_in[2];  // [512,512]
  float* out = (float*)d_out;                 // [64,512]

  char* p = (char*)d_ws;
  auto carve = [&](size_t bytes) -> char* {
    char* r = p;
    p += (bytes + 255) & ~(size_t)255;
    return r;
  };
  unsigned short* Ahi = (unsigned short*)carve((size_t)ROWS_PAD * 512 * 2);
  unsigned short* Alo = (unsigned short*)carve((size_t)ROWS_PAD * 512 * 2);
  float* logits = (float*)carve((size_t)ROWS_PAD * 512 * 4);
  unsigned short* Bh = (unsigned short*)carve((size_t)512 * 512 * 2);
  unsigned short* Bl = (unsigned short*)carve((size_t)512 * 512 * 2);
  float* pstat = (float*)carve((size_t)65792 * 8 * 4);
  float* LW = (float*)carve((size_t)65792 * 4);
  // cand [64][8][16][512] f32 = 16.8 MB aliases Ahi (dead after gemm).
  float* cand = (float*)Ahi;
  if ((size_t)(p - (char*)d_ws) > ws_size) return;

  pack_text_kernel<<<512, 128, 0, stream>>>(text, Bh, Bl);
  pack_rows_kernel<<<65536, 128, 0, stream>>>(vpat, Ahi, Alo);
  pack_cls_kernel<<<128, 128, 0, stream>>>(vcls, Ahi, Alo);
  gemm_split_kernel<<<dim3(4, 513), 256, 0, stream>>>(Ahi, Alo, Bh, Bl, logits, pstat);
  lw_kernel<<<257, 256, 0, stream>>>(pstat, LW);
  topk_partial_kernel<<<dim3(64, 2, 8), 256, 0, stream>>>(logits, LW, cand);
  topk_merge_kernel<<<128, 256, 0, stream>>>(cand, logits, LW, out);
}